// Round 1
// baseline (318.612 us; speedup 1.0000x reference)
//
#include <hip/hip_runtime.h>
#include <stdint.h>

#define B_ 2
#define T_ 2048
#define C_ 2048
#define H_ 16
#define D_ 128
#define W_ 512
#define M_ (B_*T_)      // 4096
#define N1_ (3*C_)      // 6144

typedef short bf16x8 __attribute__((ext_vector_type(8)));
typedef unsigned short u16x8 __attribute__((ext_vector_type(8)));
typedef float f32x4 __attribute__((ext_vector_type(4)));

__device__ __forceinline__ unsigned short f2bf(float f) {
  union { float f; unsigned u; } v; v.f = f;
  unsigned r = v.u + 0x7fffu + ((v.u >> 16) & 1u);
  return (unsigned short)(r >> 16);
}
__device__ __forceinline__ float bf2f(unsigned short b) {
  union { unsigned u; float f; } v; v.u = ((unsigned)b) << 16;
  return v.f;
}

__device__ __forceinline__ void gload_lds16(const void* g, void* l) {
  __builtin_amdgcn_global_load_lds((const __attribute__((address_space(1))) void*)g,
                                   (__attribute__((address_space(3))) void*)l, 16, 0, 0);
}

// ---------- fp32 -> bf16 convert (8 elems/thread) ----------
__global__ void k_cvt(const float* __restrict__ s, unsigned short* __restrict__ d, int n) {
  int i = (blockIdx.x * blockDim.x + threadIdx.x) * 8;
  if (i >= n) return;
  float4 a = *(const float4*)(s + i);
  float4 b = *(const float4*)(s + i + 4);
  u16x8 o;
  o[0]=f2bf(a.x); o[1]=f2bf(a.y); o[2]=f2bf(a.z); o[3]=f2bf(a.w);
  o[4]=f2bf(b.x); o[5]=f2bf(b.y); o[6]=f2bf(b.z); o[7]=f2bf(b.w);
  *(u16x8*)(d + i) = o;
}

// ---------- transpose + convert: src [R][Cc] f32 -> dst [Cc][R] bf16 ----------
__global__ void k_tcvt(const float* __restrict__ s, unsigned short* __restrict__ d, int R, int Cc) {
  __shared__ float tile[32][33];
  int c0 = blockIdx.x * 32, r0 = blockIdx.y * 32;
  int tx = threadIdx.x & 31, ty = threadIdx.x >> 5; // ty 0..7
  #pragma unroll
  for (int j = 0; j < 32; j += 8) tile[ty + j][tx] = s[(size_t)(r0 + ty + j) * Cc + c0 + tx];
  __syncthreads();
  #pragma unroll
  for (int j = 0; j < 32; j += 8) d[(size_t)(c0 + ty + j) * R + r0 + tx] = f2bf(tile[tx][ty + j]);
}

// ---------- GEMM: C[M][N] = A[M][K] * Bt[N][K]^T, bf16 in, f32 acc ----------
template<bool F32OUT>
__global__ __launch_bounds__(256) void k_gemm(const unsigned short* __restrict__ A,
                                              const unsigned short* __restrict__ Bt,
                                              void* __restrict__ Cp,
                                              int Ntot, int K) {
  __shared__ unsigned short As[128 * 64];
  __shared__ unsigned short Bs[128 * 64];
  const int tid = threadIdx.x;
  const int lane = tid & 63;
  const int wv = tid >> 6;
  const int wm = wv >> 1, wn = wv & 1;
  const int lr = lane & 15, lg = lane >> 4;
  const int bm0 = blockIdx.y * 128, bn0 = blockIdx.x * 128;

  f32x4 acc[4][4];
  #pragma unroll
  for (int i = 0; i < 4; ++i)
    #pragma unroll
    for (int j = 0; j < 4; ++j)
      #pragma unroll
      for (int r = 0; r < 4; ++r) acc[i][j][r] = 0.f;

  for (int k0 = 0; k0 < K; k0 += 64) {
    #pragma unroll
    for (int p = 0; p < 4; ++p) {
      int off = p * 4096 + tid * 16;       // byte offset in tile (row stride 128B)
      int row = off >> 7;
      int kb  = off & 127;
      gload_lds16(A  + (size_t)(bm0 + row) * K + k0 + (kb >> 1), (char*)As + off);
      gload_lds16(Bt + (size_t)(bn0 + row) * K + k0 + (kb >> 1), (char*)Bs + off);
    }
    __syncthreads();
    #pragma unroll
    for (int kk = 0; kk < 2; ++kk) {
      bf16x8 af[4], bfr[4];
      #pragma unroll
      for (int i = 0; i < 4; ++i)
        af[i] = *(const bf16x8*)((const char*)As + (wm*64 + i*16 + lr)*128 + kk*64 + lg*16);
      #pragma unroll
      for (int j = 0; j < 4; ++j)
        bfr[j] = *(const bf16x8*)((const char*)Bs + (wn*64 + j*16 + lr)*128 + kk*64 + lg*16);
      #pragma unroll
      for (int i = 0; i < 4; ++i)
        #pragma unroll
        for (int j = 0; j < 4; ++j)
          acc[i][j] = __builtin_amdgcn_mfma_f32_16x16x32_bf16(af[i], bfr[j], acc[i][j], 0, 0, 0);
    }
    __syncthreads();
  }
  #pragma unroll
  for (int i = 0; i < 4; ++i)
    #pragma unroll
    for (int j = 0; j < 4; ++j) {
      int m = bm0 + wm*64 + i*16 + lg*4;
      int n = bn0 + wn*64 + j*16 + lr;
      #pragma unroll
      for (int r = 0; r < 4; ++r) {
        if (F32OUT) ((float*)Cp)[(size_t)(m + r) * Ntot + n] = acc[i][j][r];
        else ((unsigned short*)Cp)[(size_t)(m + r) * Ntot + n] = f2bf(acc[i][j][r]);
      }
    }
}

// ---------- reorg: RoPE(q,k) -> (B,H,T,D); v -> v_t (B,H,D,T) ----------
__global__ __launch_bounds__(256) void k_reorg(const unsigned short* __restrict__ qkv,
                        const float* __restrict__ fcos, const float* __restrict__ fsin,
                        unsigned short* __restrict__ q_r, unsigned short* __restrict__ k_r,
                        unsigned short* __restrict__ v_t) {
  const int bh = blockIdx.x, b = bh >> 4, h = bh & 15;
  const int t0 = blockIdx.y * 64;
  const int tid = threadIdx.x;
  __shared__ unsigned short vt[64][136];
  #pragma unroll
  for (int p = 0; p < 4; ++p) {
    int idx = p * 256 + tid;
    int tl = idx >> 4, sg = idx & 15;
    int t = t0 + tl, d0 = sg * 8;
    float sgn = (d0 < 64) ? -1.f : 1.f;
    float4 c0v = *(const float4*)(fcos + t * D_ + d0);
    float4 c1v = *(const float4*)(fcos + t * D_ + d0 + 4);
    float4 s0v = *(const float4*)(fsin + t * D_ + d0);
    float4 s1v = *(const float4*)(fsin + t * D_ + d0 + 4);
    float cs[8] = {c0v.x,c0v.y,c0v.z,c0v.w,c1v.x,c1v.y,c1v.z,c1v.w};
    float sn[8] = {s0v.x,s0v.y,s0v.z,s0v.w,s1v.x,s1v.y,s1v.z,s1v.w};
    #pragma unroll
    for (int w = 0; w < 2; ++w) {
      const unsigned short* src = qkv + (size_t)(b*T_ + t) * N1_ + w*C_ + h*D_;
      u16x8 a  = *(const u16x8*)(src + d0);
      u16x8 pr = *(const u16x8*)(src + (d0 ^ 64));
      u16x8 o;
      #pragma unroll
      for (int e = 0; e < 8; ++e)
        o[e] = f2bf(bf2f(a[e]) * cs[e] + sgn * bf2f(pr[e]) * sn[e]);
      unsigned short* dst = (w ? k_r : q_r) + (size_t)((b*H_ + h)*T_ + t) * D_ + d0;
      *(u16x8*)dst = o;
    }
    const unsigned short* vsrc = qkv + (size_t)(b*T_ + t) * N1_ + 2*C_ + h*D_ + d0;
    *(u16x8*)&vt[tl][d0] = *(const u16x8*)vsrc;
  }
  __syncthreads();
  #pragma unroll
  for (int p = 0; p < 4; ++p) {
    int idx = p * 256 + tid;
    int sg = idx & 7, d = idx >> 3;
    u16x8 o;
    #pragma unroll
    for (int e = 0; e < 8; ++e) o[e] = vt[sg*8 + e][d];
    *(u16x8*)(v_t + (size_t)((b*H_ + h)*D_ + d) * T_ + t0 + sg*8) = o;
  }
}

// ---------- sliding-window flash attention ----------
__global__ __launch_bounds__(256) void k_attn(const unsigned short* __restrict__ q_r,
                       const unsigned short* __restrict__ k_r,
                       const unsigned short* __restrict__ v_t,
                       unsigned short* __restrict__ y) {
  const int bh = blockIdx.x, b = bh >> 4, h = bh & 15;
  const int q0 = blockIdx.y * 64;
  const int tid = threadIdx.x, lane = tid & 63, wv = tid >> 6;
  const int lr = lane & 15, lg = lane >> 4;

  __shared__ unsigned short Ks[64][136];   // [key][d] padded (272B rows)
  __shared__ unsigned short Vs[128][72];   // [d][key] padded (144B rows)
  __shared__ unsigned short Ps[4][16][80]; // per-wave P (160B rows)

  const size_t bhT = (size_t)(b*H_ + h) * T_;
  const unsigned short* qbase = q_r + (bhT + q0 + wv*16 + lr) * D_;
  bf16x8 qf[4];
  #pragma unroll
  for (int kk = 0; kk < 4; ++kk) qf[kk] = *(const bf16x8*)(qbase + kk*32 + lg*8);

  f32x4 o[8];
  #pragma unroll
  for (int i = 0; i < 8; ++i)
    #pragma unroll
    for (int r = 0; r < 4; ++r) o[i][r] = 0.f;
  float m_run[4], l_sum[4];
  #pragma unroll
  for (int r = 0; r < 4; ++r) { m_run[r] = -1e30f; l_sum[r] = 0.f; }

  const int i_min = q0 + wv*16, i_max = i_min + 15;
  int kt_lo = q0 - (W_ - 1); if (kt_lo < 0) kt_lo = 0; kt_lo &= ~63;
  const float scale = 0.08838834764831845f; // 1/sqrt(128)

  for (int kt = kt_lo; kt < q0 + 64; kt += 64) {
    #pragma unroll
    for (int p = 0; p < 4; ++p) {
      int idx = p*256 + tid;
      int row = idx >> 4, sg = idx & 15;
      *(u16x8*)&Ks[row][sg*8] = *(const u16x8*)(k_r + (bhT + kt + row) * D_ + sg*8);
    }
    #pragma unroll
    for (int p = 0; p < 4; ++p) {
      int idx = p*256 + tid;
      int d = idx >> 3, sg = idx & 7;
      *(u16x8*)&Vs[d][sg*8] = *(const u16x8*)(v_t + ((size_t)(b*H_+h)*D_ + d) * T_ + kt + sg*8);
    }
    __syncthreads();

    if (kt <= i_max && kt + 63 >= i_min - (W_ - 1)) {
      f32x4 s[4];
      #pragma unroll
      for (int ct = 0; ct < 4; ++ct)
        #pragma unroll
        for (int r = 0; r < 4; ++r) s[ct][r] = 0.f;
      #pragma unroll
      for (int kk = 0; kk < 4; ++kk) {
        #pragma unroll
        for (int ct = 0; ct < 4; ++ct) {
          bf16x8 kf = *(const bf16x8*)((const char*)&Ks[ct*16 + lr][0] + kk*64 + lg*16);
          s[ct] = __builtin_amdgcn_mfma_f32_16x16x32_bf16(qf[kk], kf, s[ct], 0, 0, 0);
        }
      }
      #pragma unroll
      for (int r = 0; r < 4; ++r) {
        int i = i_min + lg*4 + r;
        float sv[4];
        float rm = -1e30f;
        #pragma unroll
        for (int ct = 0; ct < 4; ++ct) {
          int j = kt + ct*16 + lr;
          bool ok = (j <= i) && (j > i - W_);
          sv[ct] = ok ? s[ct][r] * scale : -1e30f;
          rm = fmaxf(rm, sv[ct]);
        }
        #pragma unroll
        for (int msk = 1; msk < 16; msk <<= 1) rm = fmaxf(rm, __shfl_xor(rm, msk));
        float mnew = fmaxf(m_run[r], rm);
        float fac = __expf(m_run[r] - mnew);
        float rs = 0.f;
        #pragma unroll
        for (int ct = 0; ct < 4; ++ct) {
          float p = (sv[ct] > -1e29f) ? __expf(sv[ct] - mnew) : 0.f;
          rs += p;
          Ps[wv][lg*4 + r][ct*16 + lr] = f2bf(p);
        }
        #pragma unroll
        for (int msk = 1; msk < 16; msk <<= 1) rs += __shfl_xor(rs, msk);
        l_sum[r] = l_sum[r] * fac + rs;
        m_run[r] = mnew;
        #pragma unroll
        for (int nt = 0; nt < 8; ++nt) o[nt][r] *= fac;
      }
      asm volatile("s_waitcnt lgkmcnt(0)" ::: "memory");
      #pragma unroll
      for (int kk = 0; kk < 2; ++kk) {
        bf16x8 pf = *(const bf16x8*)((const char*)&Ps[wv][lr][0] + kk*64 + lg*16);
        #pragma unroll
        for (int nt = 0; nt < 8; ++nt) {
          bf16x8 vf = *(const bf16x8*)((const char*)&Vs[nt*16 + lr][0] + kk*64 + lg*16);
          o[nt] = __builtin_amdgcn_mfma_f32_16x16x32_bf16(pf, vf, o[nt], 0, 0, 0);
        }
      }
    }
    __syncthreads();
  }

  #pragma unroll
  for (int nt = 0; nt < 8; ++nt) {
    #pragma unroll
    for (int r = 0; r < 4; ++r) {
      int t = q0 + wv*16 + lg*4 + r;
      int d = nt*16 + lr;
      y[(size_t)(b*T_ + t) * C_ + h*D_ + d] = f2bf(o[nt][r] / l_sum[r]);
    }
  }
}

extern "C" void kernel_launch(void* const* d_in, const int* in_sizes, int n_in,
                              void* d_out, int out_size, void* d_ws, size_t ws_size,
                              hipStream_t stream) {
  const float* x      = (const float*)d_in[0];
  const float* fcos   = (const float*)d_in[1];
  const float* fsin   = (const float*)d_in[2];
  const float* w_attn = (const float*)d_in[3];
  const float* w_proj = (const float*)d_in[4];
  float* out = (float*)d_out;

  char* ws = (char*)d_ws;
  unsigned short* x_bf = (unsigned short*)(ws);                           // 16 MB (reused as y later)
  unsigned short* wa_t = (unsigned short*)(ws + 16777216ull);             // 24 MB
  unsigned short* wp_t = (unsigned short*)(ws + 41943040ull);             // 8 MB
  unsigned short* qkv  = (unsigned short*)(ws + 50331648ull);             // 48 MB
  unsigned short* q_r  = (unsigned short*)(ws + 100663296ull);            // 16 MB
  unsigned short* k_r  = (unsigned short*)(ws + 117440512ull);            // 16 MB
  unsigned short* v_t  = (unsigned short*)(ws + 134217728ull);            // 16 MB
  unsigned short* y_bf = x_bf;

  k_cvt<<<dim3(4096), dim3(256), 0, stream>>>(x, x_bf, M_*C_);
  k_tcvt<<<dim3(192, 64), dim3(256), 0, stream>>>(w_attn, wa_t, C_, N1_);
  k_tcvt<<<dim3(64, 64), dim3(256), 0, stream>>>(w_proj, wp_t, C_, C_);
  k_gemm<false><<<dim3(48, 32), dim3(256), 0, stream>>>(x_bf, wa_t, qkv, N1_, C_);
  k_reorg<<<dim3(32, 32), dim3(256), 0, stream>>>(qkv, fcos, fsin, q_r, k_r, v_t);
  k_attn<<<dim3(32, 32), dim3(256), 0, stream>>>(q_r, k_r, v_t, y_bf);
  k_gemm<true><<<dim3(16, 32), dim3(256), 0, stream>>>(y_bf, wp_t, out, C_, C_);
}